// Round 3
// baseline (743.404 us; speedup 1.0000x reference)
//
#include <hip/hip_runtime.h>
#include <math.h>

// GraphCNN v3: zero float atomics.
//  - edge embed via dual-CSR edge-id gather (replaces 38.4M-atomic k_eagg).
//  - conv gather reads dis-prescaled xw' rows: per-edge = 1 s_load + 1 row load.

// ---------------- node embed: h0 = x @ node_w + node_b  (K=128) ----------------
__global__ __launch_bounds__(256) void k_embed(
    const float* __restrict__ x, const float* __restrict__ w,
    const float* __restrict__ b, float* __restrict__ out, int N) {
  __shared__ __align__(16) float in_lds[64 * 132];
  const int base = blockIdx.x * 64;
  const int t = threadIdx.x;
#pragma unroll
  for (int it = 0; it < 32; ++it) {
    int lin = t + it * 256;
    int r = lin >> 7, c = lin & 127;
    int row = base + r;
    in_lds[r * 132 + c] = (row < N) ? x[(size_t)row * 128 + c] : 0.f;
  }
  __syncthreads();
  const int j = t & 63;
  const int wv = __builtin_amdgcn_readfirstlane(t >> 6);
  const float* wp = w + wv * 16;
  float acc[16];
#pragma unroll
  for (int c = 0; c < 16; ++c) acc[c] = 0.f;
#pragma unroll
  for (int k4 = 0; k4 < 32; ++k4) {
    float4 a = *(const float4*)&in_lds[j * 132 + k4 * 4];
#pragma unroll
    for (int kk = 0; kk < 4; ++kk) {
      float av = ((const float*)&a)[kk];
      int k = k4 * 4 + kk;
#pragma unroll
      for (int c = 0; c < 16; ++c)
        acc[c] = fmaf(av, wp[k * 64 + c], acc[c]);
    }
  }
  int row = base + j;
  if (row < N) {
#pragma unroll
    for (int c4 = 0; c4 < 4; ++c4) {
      float4 o;
#pragma unroll
      for (int q = 0; q < 4; ++q)
        ((float*)&o)[q] = acc[c4 * 4 + q] + b[wv * 16 + c4 * 4 + q];
      *(float4*)&out[(size_t)row * 64 + wv * 16 + c4 * 4] = o;
    }
  }
}

// ------- degree counts -------
__global__ __launch_bounds__(256) void k_count(
    const int* __restrict__ erow, const int* __restrict__ ecol,
    int* indeg, int* outdeg, int E) {
  int e = blockIdx.x * 256 + threadIdx.x;
  if (e < E) {
    atomicAdd(&indeg[ecol[e]], 1);
    atomicAdd(&outdeg[erow[e]], 1);
  }
}

// ------- exclusive scan (3 kernels, chunk=1024) -------
__global__ __launch_bounds__(256) void k_scanA(
    const int* __restrict__ cnt, int* __restrict__ off,
    int* __restrict__ chunk_sum, int N) {
  __shared__ int sc[256];
  int b = blockIdx.x, t = threadIdx.x;
  int i0 = b * 1024 + t * 4;
  int v[4];
  int s = 0;
#pragma unroll
  for (int q = 0; q < 4; ++q) {
    v[q] = (i0 + q < N) ? cnt[i0 + q] : 0;
    s += v[q];
  }
  sc[t] = s;
  __syncthreads();
  for (int d = 1; d < 256; d <<= 1) {
    int x = (t >= d) ? sc[t - d] : 0;
    __syncthreads();
    sc[t] += x;
    __syncthreads();
  }
  int run = sc[t] - s;
#pragma unroll
  for (int q = 0; q < 4; ++q) {
    if (i0 + q < N) off[i0 + q] = run;
    run += v[q];
  }
  if (t == 255) chunk_sum[b] = sc[255];
}

__global__ __launch_bounds__(128) void k_scanB(
    const int* __restrict__ chunk_sum, int* __restrict__ chunk_base, int nch) {
  __shared__ int sc[128];
  int t = threadIdx.x;
  int s = (t < nch) ? chunk_sum[t] : 0;
  sc[t] = s;
  __syncthreads();
  for (int d = 1; d < 128; d <<= 1) {
    int x = (t >= d) ? sc[t - d] : 0;
    __syncthreads();
    sc[t] += x;
    __syncthreads();
  }
  if (t < nch) chunk_base[t] = sc[t] - s;
}

__global__ __launch_bounds__(256) void k_scanC(
    int* __restrict__ off, const int* __restrict__ chunk_base,
    int* __restrict__ cursor, int N) {
  int i = blockIdx.x * 256 + threadIdx.x;
  if (i < N) {
    int v = off[i] + chunk_base[i >> 10];
    off[i] = v;
    cursor[i] = v;
  }
}

// ------- dual CSR fill: by-col {src,eid}, by-row {eid} -------
__global__ __launch_bounds__(256) void k_fill(
    const int* __restrict__ erow, const int* __restrict__ ecol,
    int* cursor_c, int* cursor_r, int* __restrict__ srclst,
    int* __restrict__ eidc, int* __restrict__ eidr, int E) {
  int e = blockIdx.x * 256 + threadIdx.x;
  if (e < E) {
    int r = erow[e], c = ecol[e];
    int pc = atomicAdd(&cursor_c[c], 1);
    srclst[pc] = r;
    eidc[pc] = e;
    int pr = atomicAdd(&cursor_r[r], 1);
    eidr[pr] = e;
  }
}

// ------- edge-embed gather: acc16[n] = sum of ea[eid] over incident edges -------
// wave per node: 4 edge-slots x 16 features; cross-slot shfl reduce.
__global__ __launch_bounds__(256) void k_egather(
    const float* __restrict__ ea, const int* __restrict__ eidc,
    const int* __restrict__ eidr, const int* __restrict__ offc_,
    const int* __restrict__ indeg, const int* __restrict__ offr_,
    const int* __restrict__ outdeg, float* __restrict__ acc16, int N) {
  int t = blockIdx.x * 256 + threadIdx.x;
  int n = __builtin_amdgcn_readfirstlane(t >> 6);
  if (n >= N) return;
  int lane = threadIdx.x & 63;
  int slot = lane >> 4, kk = lane & 15;
  int offc = offc_[n], cin = indeg[n];
  int offr = offr_[n], cout = outdeg[n];
  float acc = 0.f;
  for (int i = 0; i < cin; i += 4) {
    int idx = i + slot;
    int eid = (idx < cin) ? eidc[offc + idx] : -1;
    if (eid >= 0) acc += ea[(size_t)eid * 16 + kk];
  }
  for (int i = 0; i < cout; i += 4) {
    int idx = i + slot;
    int eid = (idx < cout) ? eidr[offr + idx] : -1;
    if (eid >= 0) acc += ea[(size_t)eid * 16 + kk];
  }
  acc += __shfl_xor(acc, 16, 64);
  acc += __shfl_xor(acc, 32, 64);
  if (lane < 16) acc16[(size_t)n * 16 + lane] = acc;
}

// ------- fused edge GEMM: h0 += acc16 @ ew + (indeg+outdeg)*eb ; dis -------
__global__ __launch_bounds__(256) void k_edgemm(
    const float* __restrict__ acc16, const float* __restrict__ ew,
    const float* __restrict__ eb, const int* __restrict__ indeg,
    const int* __restrict__ outdeg, float* h0, float* __restrict__ dis, int N) {
  int t = blockIdx.x * 256 + threadIdx.x;
  int j = t & 63;
  int n = __builtin_amdgcn_readfirstlane(t >> 6);
  if (n >= N) return;
  int id = indeg[n], od = outdeg[n];
  const float* a = acc16 + (size_t)n * 16;  // wave-uniform -> s_load
  float v = h0[(size_t)n * 64 + j] + (float)(id + od) * eb[j];
#pragma unroll
  for (int k = 0; k < 16; ++k)
    v = fmaf(a[k], ew[k * 64 + j], v);
  h0[(size_t)n * 64 + j] = v;
  if (j == 0) dis[n] = 1.0f / sqrtf((float)id + 1.0f);
}

// ------- conv GEMM with dis-prescale: xws = dis * (h @ w) -------
__global__ __launch_bounds__(256) void k_conv(
    const float* __restrict__ hin, const float* __restrict__ w,
    const float* __restrict__ dis, float* __restrict__ xws, int N) {
  __shared__ __align__(16) float in_lds[64 * 68];
  const int base = blockIdx.x * 64;
  const int t = threadIdx.x;
#pragma unroll
  for (int it = 0; it < 16; ++it) {
    int lin = t + it * 256;
    int r = lin >> 6, c = lin & 63;
    int row = base + r;
    in_lds[r * 68 + c] = (row < N) ? hin[(size_t)row * 64 + c] : 0.f;
  }
  __syncthreads();
  const int j = t & 63;
  const int wv = __builtin_amdgcn_readfirstlane(t >> 6);
  const float* wp = w + wv * 16;
  float acc[16];
#pragma unroll
  for (int c = 0; c < 16; ++c) acc[c] = 0.f;
#pragma unroll
  for (int k4 = 0; k4 < 16; ++k4) {
    float4 a = *(const float4*)&in_lds[j * 68 + k4 * 4];
#pragma unroll
    for (int kk = 0; kk < 4; ++kk) {
      float av = ((const float*)&a)[kk];
      int k = k4 * 4 + kk;
#pragma unroll
      for (int c = 0; c < 16; ++c)
        acc[c] = fmaf(av, wp[k * 64 + c], acc[c]);
    }
  }
  int row = base + j;
  if (row < N) {
    float d = dis[row];
#pragma unroll
    for (int c4 = 0; c4 < 4; ++c4) {
      float4 o;
#pragma unroll
      for (int q = 0; q < 4; ++q)
        ((float*)&o)[q] = d * acc[c4 * 4 + q];
      *(float4*)&xws[(size_t)row * 64 + wv * 16 + c4 * 4] = o;
    }
  }
}

// ------- gather: h_new[n] = relu( dis_n * (xws[n] + sum_src xws[src]) + b ) -------
__global__ __launch_bounds__(256) void k_gather(
    const float* __restrict__ xws, const float* __restrict__ dis,
    const int* __restrict__ csr_off, const int* __restrict__ indeg,
    const int* __restrict__ src_list, const float* __restrict__ b,
    float* __restrict__ h0, float* __restrict__ hj_slice, int N) {
  int t = blockIdx.x * 256 + threadIdx.x;
  int j = t & 63;
  int n = __builtin_amdgcn_readfirstlane(t >> 6);
  if (n >= N) return;
  float acc = xws[(size_t)n * 64 + j];
  int off = csr_off[n], cnt = indeg[n];
  int k = 0;
  for (; k + 8 <= cnt; k += 8) {
    int r0 = src_list[off + k + 0], r1 = src_list[off + k + 1];
    int r2 = src_list[off + k + 2], r3 = src_list[off + k + 3];
    int r4 = src_list[off + k + 4], r5 = src_list[off + k + 5];
    int r6 = src_list[off + k + 6], r7 = src_list[off + k + 7];
    float v0 = xws[(size_t)r0 * 64 + j], v1 = xws[(size_t)r1 * 64 + j];
    float v2 = xws[(size_t)r2 * 64 + j], v3 = xws[(size_t)r3 * 64 + j];
    float v4 = xws[(size_t)r4 * 64 + j], v5 = xws[(size_t)r5 * 64 + j];
    float v6 = xws[(size_t)r6 * 64 + j], v7 = xws[(size_t)r7 * 64 + j];
    acc += v0 + v1 + v2 + v3 + v4 + v5 + v6 + v7;
  }
  for (; k + 4 <= cnt; k += 4) {
    int r0 = src_list[off + k + 0], r1 = src_list[off + k + 1];
    int r2 = src_list[off + k + 2], r3 = src_list[off + k + 3];
    float v0 = xws[(size_t)r0 * 64 + j], v1 = xws[(size_t)r1 * 64 + j];
    float v2 = xws[(size_t)r2 * 64 + j], v3 = xws[(size_t)r3 * 64 + j];
    acc += v0 + v1 + v2 + v3;
  }
  for (; k < cnt; ++k) {
    int r = src_list[off + k];
    acc += xws[(size_t)r * 64 + j];
  }
  float act = fmaxf(fmaf(dis[n], acc, b[j]), 0.f);
  h0[(size_t)n * 64 + j] = act;
  hj_slice[(size_t)n * 192 + j] = act;
}

// ------- mean-pool (batch sorted -> binary search) + classifier -------
__global__ __launch_bounds__(192) void k_pool(
    const float* __restrict__ hj, const int* __restrict__ batch, int N,
    const float* __restrict__ w1, const float* __restrict__ b1,
    const float* __restrict__ w2, const float* __restrict__ b2,
    float* __restrict__ out) {
  __shared__ float pl[192];
  int g = blockIdx.x;
  int t = threadIdx.x;
  int lo = 0, hi = N;
  while (lo < hi) { int m = (lo + hi) >> 1; if (batch[m] < g) lo = m + 1; else hi = m; }
  int start = lo;
  hi = N;
  while (lo < hi) { int m = (lo + hi) >> 1; if (batch[m] < g + 1) lo = m + 1; else hi = m; }
  int end = lo;
  float s = 0.f;
  for (int r = start; r < end; ++r) s += hj[(size_t)r * 192 + t];
  int cnt = end - start;
  pl[t] = s / (float)(cnt > 0 ? cnt : 1);
  __syncthreads();
  if (t < 64) {
    float val = 0.f;
    if (t < 32) {
      float z = b1[t];
#pragma unroll 8
      for (int k = 0; k < 192; ++k) z = fmaf(pl[k], w1[k * 32 + t], z);
      z = fmaxf(z, 0.f);
      val = z * w2[t];
    }
#pragma unroll
    for (int off = 16; off > 0; off >>= 1) val += __shfl_down(val, off);
    if (t == 0) out[g] = val + b2[0];
  }
}

extern "C" void kernel_launch(void* const* d_in, const int* in_sizes, int n_in,
                              void* d_out, int out_size, void* d_ws, size_t ws_size,
                              hipStream_t stream) {
  const float* x      = (const float*)d_in[0];
  const float* ea     = (const float*)d_in[1];
  const float* node_w = (const float*)d_in[2];
  const float* node_b = (const float*)d_in[3];
  const float* edge_w = (const float*)d_in[4];
  const float* edge_b = (const float*)d_in[5];
  const float* conv_w = (const float*)d_in[6];
  const float* conv_b = (const float*)d_in[7];
  const float* w1     = (const float*)d_in[8];
  const float* b1     = (const float*)d_in[9];
  const float* w2     = (const float*)d_in[10];
  const float* b2     = (const float*)d_in[11];
  const int*   ei     = (const int*)d_in[12];
  const int*   batch  = (const int*)d_in[13];

  const int N = in_sizes[0] / 128;
  const int E = in_sizes[12] / 2;
  const int G = out_size;
  const int* erow = ei;
  const int* ecol = ei + E;

  float* ws = (float*)d_ws;
  size_t o = 0;
  float* h0    = ws + o; o += (size_t)N * 64;
  float* xws   = ws + o; o += (size_t)N * 64;   // acc16 aliases its head (N*16)
  float* hj    = ws + o; o += (size_t)N * 192;  // eidc/eidr alias its head (2E ints)
  float* dis   = ws + o; o += N;
  int* indeg   = (int*)(ws + o); o += N;
  int* outdeg  = (int*)(ws + o); o += N;
  int* csoffc  = (int*)(ws + o); o += N;
  int* csoffr  = (int*)(ws + o); o += N;
  int* cursc   = (int*)(ws + o); o += N;
  int* cursr   = (int*)(ws + o); o += N;
  int* chsum   = (int*)(ws + o); o += 128;
  int* chbase  = (int*)(ws + o); o += 128;
  int* srclst  = (int*)(ws + o); o += E;
  float* acc16 = xws;                 // consumed by k_edgemm before convs write xws
  int* eidc    = (int*)hj;            // consumed by k_egather before gathers write hj
  int* eidr    = (int*)hj + E;
  float* out = (float*)d_out;

  const int nch = (N + 1023) / 1024;
  dim3 b256(256);

  hipMemsetAsync(indeg, 0, (size_t)N * sizeof(int), stream);
  hipMemsetAsync(outdeg, 0, (size_t)N * sizeof(int), stream);

  k_embed<<<(N + 63) / 64, b256, 0, stream>>>(x, node_w, node_b, h0, N);
  k_count<<<(E + 255) / 256, b256, 0, stream>>>(erow, ecol, indeg, outdeg, E);
  k_scanA<<<nch, b256, 0, stream>>>(indeg, csoffc, chsum, N);
  k_scanB<<<1, dim3(128), 0, stream>>>(chsum, chbase, nch);
  k_scanC<<<(N + 255) / 256, b256, 0, stream>>>(csoffc, chbase, cursc, N);
  k_scanA<<<nch, b256, 0, stream>>>(outdeg, csoffr, chsum, N);
  k_scanB<<<1, dim3(128), 0, stream>>>(chsum, chbase, nch);
  k_scanC<<<(N + 255) / 256, b256, 0, stream>>>(csoffr, chbase, cursr, N);
  k_fill<<<(E + 255) / 256, b256, 0, stream>>>(erow, ecol, cursc, cursr,
                                               srclst, eidc, eidr, E);
  k_egather<<<((size_t)N * 64 + 255) / 256, b256, 0, stream>>>(
      ea, eidc, eidr, csoffc, indeg, csoffr, outdeg, acc16, N);
  k_edgemm<<<((size_t)N * 64 + 255) / 256, b256, 0, stream>>>(
      acc16, edge_w, edge_b, indeg, outdeg, h0, dis, N);
  for (int l = 0; l < 3; ++l) {
    k_conv<<<(N + 63) / 64, b256, 0, stream>>>(
        h0, conv_w + (size_t)l * 64 * 64, dis, xws, N);
    k_gather<<<((size_t)N * 64 + 255) / 256, b256, 0, stream>>>(
        xws, dis, csoffc, indeg, srclst, conv_b + (size_t)l * 64,
        h0, hj + (size_t)l * 64, N);
  }
  k_pool<<<G, dim3(192), 0, stream>>>(hj, batch, N, w1, b1, w2, b2, out);
}

// Round 4
// 640.859 us; speedup vs baseline: 1.1600x; 1.1600x over previous
//
#include <hip/hip_runtime.h>
#include <math.h>

// GraphCNN v4:
//  - single by-col CSR, packed int2{src,eid}: 1 atomic + 1x8B scattered store/edge
//    (v3's 3-stream fill had 13x write amplification -> 206us).
//  - edge-embed col-part gathered from CSR (.y); row-part via 19.2M atomics.
//  - gather kernels issue 16 clamped loads in flight (avg deg 12 -> 1 latency round).

#define ATOM(p, v) unsafeAtomicAdd((p), (v))

// ---------------- node embed: h0 = x @ node_w + node_b  (K=128) ----------------
__global__ __launch_bounds__(256) void k_embed(
    const float* __restrict__ x, const float* __restrict__ w,
    const float* __restrict__ b, float* __restrict__ out, int N) {
  __shared__ __align__(16) float in_lds[64 * 132];
  const int base = blockIdx.x * 64;
  const int t = threadIdx.x;
#pragma unroll
  for (int it = 0; it < 32; ++it) {
    int lin = t + it * 256;
    int r = lin >> 7, c = lin & 127;
    int row = base + r;
    in_lds[r * 132 + c] = (row < N) ? x[(size_t)row * 128 + c] : 0.f;
  }
  __syncthreads();
  const int j = t & 63;
  const int wv = __builtin_amdgcn_readfirstlane(t >> 6);
  const float* wp = w + wv * 16;
  float acc[16];
#pragma unroll
  for (int c = 0; c < 16; ++c) acc[c] = 0.f;
#pragma unroll
  for (int k4 = 0; k4 < 32; ++k4) {
    float4 a = *(const float4*)&in_lds[j * 132 + k4 * 4];
#pragma unroll
    for (int kk = 0; kk < 4; ++kk) {
      float av = ((const float*)&a)[kk];
      int k = k4 * 4 + kk;
#pragma unroll
      for (int c = 0; c < 16; ++c)
        acc[c] = fmaf(av, wp[k * 64 + c], acc[c]);
    }
  }
  int row = base + j;
  if (row < N) {
#pragma unroll
    for (int c4 = 0; c4 < 4; ++c4) {
      float4 o;
#pragma unroll
      for (int q = 0; q < 4; ++q)
        ((float*)&o)[q] = acc[c4 * 4 + q] + b[wv * 16 + c4 * 4 + q];
      *(float4*)&out[(size_t)row * 64 + wv * 16 + c4 * 4] = o;
    }
  }
}

// ------- degree counts -------
__global__ __launch_bounds__(256) void k_count(
    const int* __restrict__ erow, const int* __restrict__ ecol,
    int* indeg, int* outdeg, int E) {
  int e = blockIdx.x * 256 + threadIdx.x;
  if (e < E) {
    atomicAdd(&indeg[ecol[e]], 1);
    atomicAdd(&outdeg[erow[e]], 1);
  }
}

// ------- exclusive scan (3 kernels, chunk=1024) -------
__global__ __launch_bounds__(256) void k_scanA(
    const int* __restrict__ cnt, int* __restrict__ off,
    int* __restrict__ chunk_sum, int N) {
  __shared__ int sc[256];
  int b = blockIdx.x, t = threadIdx.x;
  int i0 = b * 1024 + t * 4;
  int v[4];
  int s = 0;
#pragma unroll
  for (int q = 0; q < 4; ++q) {
    v[q] = (i0 + q < N) ? cnt[i0 + q] : 0;
    s += v[q];
  }
  sc[t] = s;
  __syncthreads();
  for (int d = 1; d < 256; d <<= 1) {
    int x = (t >= d) ? sc[t - d] : 0;
    __syncthreads();
    sc[t] += x;
    __syncthreads();
  }
  int run = sc[t] - s;
#pragma unroll
  for (int q = 0; q < 4; ++q) {
    if (i0 + q < N) off[i0 + q] = run;
    run += v[q];
  }
  if (t == 255) chunk_sum[b] = sc[255];
}

__global__ __launch_bounds__(128) void k_scanB(
    const int* __restrict__ chunk_sum, int* __restrict__ chunk_base, int nch) {
  __shared__ int sc[128];
  int t = threadIdx.x;
  int s = (t < nch) ? chunk_sum[t] : 0;
  sc[t] = s;
  __syncthreads();
  for (int d = 1; d < 128; d <<= 1) {
    int x = (t >= d) ? sc[t - d] : 0;
    __syncthreads();
    sc[t] += x;
    __syncthreads();
  }
  if (t < nch) chunk_base[t] = sc[t] - s;
}

__global__ __launch_bounds__(256) void k_scanC(
    int* __restrict__ off, const int* __restrict__ chunk_base, int N) {
  int i = blockIdx.x * 256 + threadIdx.x;
  if (i < N) off[i] += chunk_base[i >> 10];
}

// ------- CSR fill: lst2[pos++] = {src, eid}; csend mutates start->end offsets -------
__global__ __launch_bounds__(256) void k_fill(
    const int* __restrict__ erow, const int* __restrict__ ecol,
    int* csend, int2* __restrict__ lst2, int E) {
  int e = blockIdx.x * 256 + threadIdx.x;
  if (e < E) {
    int r = erow[e], c = ecol[e];
    int pos = atomicAdd(&csend[c], 1);
    int2 v; v.x = r; v.y = e;
    lst2[pos] = v;
  }
}

// ------- edge-embed col-part: acc16[n] = sum ea[eid] over by-col edges (init) -------
__global__ __launch_bounds__(256) void k_egc(
    const float* __restrict__ ea, const int2* __restrict__ lst2,
    const int* __restrict__ csend, const int* __restrict__ indeg,
    float* __restrict__ acc16, int N) {
  int t = blockIdx.x * 256 + threadIdx.x;
  int n = __builtin_amdgcn_readfirstlane(t >> 6);
  if (n >= N) return;
  int lane = threadIdx.x & 63;
  int slot = lane >> 4, kk = lane & 15;
  int cnt = indeg[n];
  int base = csend[n] - cnt;
  int c0 = (cnt > 0) ? cnt - 1 : 0;
  float acc = 0.f;
  for (int i = 0; i < cnt; i += 16) {
#pragma unroll
    for (int q = 0; q < 4; ++q) {
      int idx = i + q * 4 + slot;
      int eid = lst2[base + min(idx, c0)].y;
      float v = ea[(size_t)eid * 16 + kk];
      acc += (idx < cnt) ? v : 0.f;
    }
  }
  acc += __shfl_xor(acc, 16, 64);
  acc += __shfl_xor(acc, 32, 64);
  if (lane < 16) acc16[(size_t)n * 16 + lane] = acc;
}

// ------- edge-embed row-part: acc16[row] += ea[e] (atomic) -------
__global__ __launch_bounds__(256) void k_eaggrow(
    const float* __restrict__ ea, const int* __restrict__ erow,
    float* acc16, int E) {
  int t = blockIdx.x * 256 + threadIdx.x;
  int e = t >> 4, k = t & 15;
  if (e >= E) return;
  ATOM(&acc16[(size_t)erow[e] * 16 + k], ea[(size_t)e * 16 + k]);
}

// ------- fused edge GEMM: h0 += acc16 @ ew + (indeg+outdeg)*eb ; dis -------
__global__ __launch_bounds__(256) void k_edgemm(
    const float* __restrict__ acc16, const float* __restrict__ ew,
    const float* __restrict__ eb, const int* __restrict__ indeg,
    const int* __restrict__ outdeg, float* h0, float* __restrict__ dis, int N) {
  int t = blockIdx.x * 256 + threadIdx.x;
  int j = t & 63;
  int n = __builtin_amdgcn_readfirstlane(t >> 6);
  if (n >= N) return;
  int id = indeg[n], od = outdeg[n];
  const float* a = acc16 + (size_t)n * 16;  // wave-uniform -> s_load
  float v = h0[(size_t)n * 64 + j] + (float)(id + od) * eb[j];
#pragma unroll
  for (int k = 0; k < 16; ++k)
    v = fmaf(a[k], ew[k * 64 + j], v);
  h0[(size_t)n * 64 + j] = v;
  if (j == 0) dis[n] = 1.0f / sqrtf((float)id + 1.0f);
}

// ------- conv GEMM with dis-prescale: xws = dis * (h @ w) -------
__global__ __launch_bounds__(256) void k_conv(
    const float* __restrict__ hin, const float* __restrict__ w,
    const float* __restrict__ dis, float* __restrict__ xws, int N) {
  __shared__ __align__(16) float in_lds[64 * 68];
  const int base = blockIdx.x * 64;
  const int t = threadIdx.x;
#pragma unroll
  for (int it = 0; it < 16; ++it) {
    int lin = t + it * 256;
    int r = lin >> 6, c = lin & 63;
    int row = base + r;
    in_lds[r * 68 + c] = (row < N) ? hin[(size_t)row * 64 + c] : 0.f;
  }
  __syncthreads();
  const int j = t & 63;
  const int wv = __builtin_amdgcn_readfirstlane(t >> 6);
  const float* wp = w + wv * 16;
  float acc[16];
#pragma unroll
  for (int c = 0; c < 16; ++c) acc[c] = 0.f;
#pragma unroll
  for (int k4 = 0; k4 < 16; ++k4) {
    float4 a = *(const float4*)&in_lds[j * 68 + k4 * 4];
#pragma unroll
    for (int kk = 0; kk < 4; ++kk) {
      float av = ((const float*)&a)[kk];
      int k = k4 * 4 + kk;
#pragma unroll
      for (int c = 0; c < 16; ++c)
        acc[c] = fmaf(av, wp[k * 64 + c], acc[c]);
    }
  }
  int row = base + j;
  if (row < N) {
    float d = dis[row];
#pragma unroll
    for (int c4 = 0; c4 < 4; ++c4) {
      float4 o;
#pragma unroll
      for (int q = 0; q < 4; ++q)
        ((float*)&o)[q] = d * acc[c4 * 4 + q];
      *(float4*)&xws[(size_t)row * 64 + wv * 16 + c4 * 4] = o;
    }
  }
}

// ------- gather: h_new = relu( dis_n * (xws[n] + sum_src xws[src]) + b ) -------
// 16 row-loads in flight per iteration (index-clamped, masked accumulate).
__global__ __launch_bounds__(256) void k_gather(
    const float* __restrict__ xws, const float* __restrict__ dis,
    const int* __restrict__ csend, const int* __restrict__ indeg,
    const int2* __restrict__ lst2, const float* __restrict__ b,
    float* __restrict__ h0, float* __restrict__ hj_slice, int N) {
  int t = blockIdx.x * 256 + threadIdx.x;
  int j = t & 63;
  int n = __builtin_amdgcn_readfirstlane(t >> 6);
  if (n >= N) return;
  int cnt = indeg[n];
  int base = csend[n] - cnt;
  int c0 = (cnt > 0) ? cnt - 1 : 0;
  float acc = xws[(size_t)n * 64 + j];
  for (int i = 0; i < cnt; i += 16) {
    float s[16];
#pragma unroll
    for (int q = 0; q < 16; ++q) {
      int src = lst2[base + min(i + q, c0)].x;
      s[q] = xws[(size_t)src * 64 + j];
    }
#pragma unroll
    for (int q = 0; q < 16; ++q)
      acc += (i + q < cnt) ? s[q] : 0.f;
  }
  float act = fmaxf(fmaf(dis[n], acc, b[j]), 0.f);
  h0[(size_t)n * 64 + j] = act;
  hj_slice[(size_t)n * 192 + j] = act;
}

// ------- mean-pool (batch sorted -> binary search) + classifier -------
__global__ __launch_bounds__(192) void k_pool(
    const float* __restrict__ hj, const int* __restrict__ batch, int N,
    const float* __restrict__ w1, const float* __restrict__ b1,
    const float* __restrict__ w2, const float* __restrict__ b2,
    float* __restrict__ out) {
  __shared__ float pl[192];
  int g = blockIdx.x;
  int t = threadIdx.x;
  int lo = 0, hi = N;
  while (lo < hi) { int m = (lo + hi) >> 1; if (batch[m] < g) lo = m + 1; else hi = m; }
  int start = lo;
  hi = N;
  while (lo < hi) { int m = (lo + hi) >> 1; if (batch[m] < g + 1) lo = m + 1; else hi = m; }
  int end = lo;
  float s = 0.f;
  for (int r = start; r < end; ++r) s += hj[(size_t)r * 192 + t];
  int cnt = end - start;
  pl[t] = s / (float)(cnt > 0 ? cnt : 1);
  __syncthreads();
  if (t < 64) {
    float val = 0.f;
    if (t < 32) {
      float z = b1[t];
#pragma unroll 8
      for (int k = 0; k < 192; ++k) z = fmaf(pl[k], w1[k * 32 + t], z);
      z = fmaxf(z, 0.f);
      val = z * w2[t];
    }
#pragma unroll
    for (int off = 16; off > 0; off >>= 1) val += __shfl_down(val, off);
    if (t == 0) out[g] = val + b2[0];
  }
}

extern "C" void kernel_launch(void* const* d_in, const int* in_sizes, int n_in,
                              void* d_out, int out_size, void* d_ws, size_t ws_size,
                              hipStream_t stream) {
  const float* x      = (const float*)d_in[0];
  const float* ea     = (const float*)d_in[1];
  const float* node_w = (const float*)d_in[2];
  const float* node_b = (const float*)d_in[3];
  const float* edge_w = (const float*)d_in[4];
  const float* edge_b = (const float*)d_in[5];
  const float* conv_w = (const float*)d_in[6];
  const float* conv_b = (const float*)d_in[7];
  const float* w1     = (const float*)d_in[8];
  const float* b1     = (const float*)d_in[9];
  const float* w2     = (const float*)d_in[10];
  const float* b2     = (const float*)d_in[11];
  const int*   ei     = (const int*)d_in[12];
  const int*   batch  = (const int*)d_in[13];

  const int N = in_sizes[0] / 128;
  const int E = in_sizes[12] / 2;
  const int G = out_size;
  const int* erow = ei;
  const int* ecol = ei + E;

  float* ws = (float*)d_ws;
  size_t o = 0;
  float* h0    = ws + o; o += (size_t)N * 64;
  float* xws   = ws + o; o += (size_t)N * 64;   // acc16 aliases head (N*16)
  float* hj    = ws + o; o += (size_t)N * 192;
  float* dis   = ws + o; o += N;
  int* indeg   = (int*)(ws + o); o += N;
  int* outdeg  = (int*)(ws + o); o += N;
  int* csend   = (int*)(ws + o); o += N;
  int* chsum   = (int*)(ws + o); o += 128;
  int* chbase  = (int*)(ws + o); o += 128;
  int2* lst2   = (int2*)(ws + o); o += (size_t)2 * E;
  float* acc16 = xws;
  float* out = (float*)d_out;

  const int nch = (N + 1023) / 1024;
  dim3 b256(256);

  hipMemsetAsync(indeg, 0, (size_t)N * sizeof(int), stream);
  hipMemsetAsync(outdeg, 0, (size_t)N * sizeof(int), stream);

  k_embed<<<(N + 63) / 64, b256, 0, stream>>>(x, node_w, node_b, h0, N);
  k_count<<<(E + 255) / 256, b256, 0, stream>>>(erow, ecol, indeg, outdeg, E);
  k_scanA<<<nch, b256, 0, stream>>>(indeg, csend, chsum, N);
  k_scanB<<<1, dim3(128), 0, stream>>>(chsum, chbase, nch);
  k_scanC<<<(N + 255) / 256, b256, 0, stream>>>(csend, chbase, N);
  k_fill<<<(E + 255) / 256, b256, 0, stream>>>(erow, ecol, csend, lst2, E);
  k_egc<<<((size_t)N * 64 + 255) / 256, b256, 0, stream>>>(
      ea, lst2, csend, indeg, acc16, N);
  k_eaggrow<<<((size_t)E * 16 + 255) / 256, b256, 0, stream>>>(ea, erow, acc16, E);
  k_edgemm<<<((size_t)N * 64 + 255) / 256, b256, 0, stream>>>(
      acc16, edge_w, edge_b, indeg, outdeg, h0, dis, N);
  for (int l = 0; l < 3; ++l) {
    k_conv<<<(N + 63) / 64, b256, 0, stream>>>(
        h0, conv_w + (size_t)l * 64 * 64, dis, xws, N);
    k_gather<<<((size_t)N * 64 + 255) / 256, b256, 0, stream>>>(
        xws, dis, csend, indeg, lst2, conv_b + (size_t)l * 64,
        h0, hj + (size_t)l * 64, N);
  }
  k_pool<<<G, dim3(192), 0, stream>>>(hj, batch, N, w1, b1, w2, b2, out);
}